// Round 3
// baseline (1856.725 us; speedup 1.0000x reference)
//
#include <hip/hip_runtime.h>

// ---------------------------------------------------------------------------
// CriticWithGNN: only nodes < n_agents reach the output, so only edges with
// receiver < n_agents (~2% of E) need the message MLP. FLOPs: 210G -> ~5G.
// R3: register-double-buffered weight chunks (latency hiding); edge grid=1024.
// ---------------------------------------------------------------------------

#define STRIDE 260   // LDS row stride in words (mult of 4 for float4, 260%32=4)

// Compact edges with receiver < n_agents. LDS-staged so each block does ONE
// global atomicAdd (avoids thousands of serialized same-address atomics).
#define FILT_CHUNK 4096
__global__ void filter_edges(const int* __restrict__ senders,
                             const int* __restrict__ receivers,
                             int E, int n_agents, int cap,
                             int* __restrict__ counter, int2* __restrict__ edges) {
    __shared__ int lcount;
    __shared__ int lbase;
    __shared__ int2 lbuf[FILT_CHUNK];
    if (threadIdx.x == 0) lcount = 0;
    __syncthreads();
    int start = blockIdx.x * FILT_CHUNK;
    int end = min(start + FILT_CHUNK, E);
    for (int idx = start + (int)threadIdx.x; idx < end; idx += 256) {
        int r = receivers[idx];
        if (r < n_agents) {
            int p = atomicAdd(&lcount, 1);
            lbuf[p] = make_int2(senders[idx], r);
        }
    }
    __syncthreads();
    if (threadIdx.x == 0) lbase = atomicAdd(counter, lcount);
    __syncthreads();
    for (int i = (int)threadIdx.x; i < lcount; i += 256) {
        int pos = lbase + i;
        if (pos < cap) edges[pos] = lbuf[i];
    }
}

// Dense layer on an LDS tile: out[TE][NOUT] = act(in[TE][NIN] @ W + b).
// T threads; thread computes COLS consecutive out-cols for ER rows.
// Weights streamed through a register DOUBLE BUFFER in chunks of KC rows:
// chunk c+1's KC independent loads are issued while chunk c is consumed,
// hiding L2 latency. LDS in-reads are wave-broadcast (lanes share row).
template<int T, int TE, int NIN, int NOUT, int COLS, int KC, bool RELU, int OOFF>
__device__ __forceinline__ void mlp_layer(const float* in_lds, float* out_lds,
                                          const float* __restrict__ W,
                                          const float* __restrict__ b) {
    constexpr int TX = NOUT / COLS;
    constexpr int G  = T / TX;
    static_assert(TE % G == 0, "rows must split evenly over thread groups");
    constexpr int ER = TE / G;
    static_assert(NIN % KC == 0 && KC % 4 == 0, "chunking");
    constexpr int NCH = NIN / KC;

    const int t  = (int)threadIdx.x;
    const int tx = t % TX;
    const int g  = t / TX;
    const int o  = tx * COLS;
    const int e0 = g * ER;

    float acc[ER][COLS];
#pragma unroll
    for (int er = 0; er < ER; ++er)
#pragma unroll
        for (int c = 0; c < COLS; ++c) acc[er][c] = 0.f;

    float w[2][KC][COLS];

    auto loadW = [&](int buf, int k0) {
#pragma unroll
        for (int kk = 0; kk < KC; ++kk) {
            const float* wp = W + (size_t)(k0 + kk) * NOUT + o;
            if (COLS == 4) {
                float4 v = *(const float4*)wp;
                w[buf][kk][0] = v.x; w[buf][kk][1] = v.y;
                w[buf][kk][2] = v.z; w[buf][kk][3] = v.w;
            } else {
                float2 v = *(const float2*)wp;
                w[buf][kk][0] = v.x; w[buf][kk][1] = v.y;
            }
        }
    };
    auto computeW = [&](int buf, int k0) {
#pragma unroll
        for (int kk = 0; kk < KC; kk += 4) {
#pragma unroll
            for (int er = 0; er < ER; ++er) {
                float4 a = *(const float4*)(in_lds + (e0 + er) * STRIDE + k0 + kk);
#pragma unroll
                for (int c = 0; c < COLS; ++c) {
                    acc[er][c] += a.x * w[buf][kk + 0][c] + a.y * w[buf][kk + 1][c]
                                + a.z * w[buf][kk + 2][c] + a.w * w[buf][kk + 3][c];
                }
            }
        }
    };

    loadW(0, 0);
#pragma unroll
    for (int ch = 0; ch < NCH - 1; ++ch) {
        loadW((ch + 1) & 1, (ch + 1) * KC);
        computeW(ch & 1, ch * KC);
    }
    computeW((NCH - 1) & 1, (NCH - 1) * KC);

#pragma unroll
    for (int er = 0; er < ER; ++er) {
        float v[COLS];
#pragma unroll
        for (int c = 0; c < COLS; ++c) {
            v[c] = acc[er][c] + b[o + c];
            if (RELU) v[c] = fmaxf(v[c], 0.f);
        }
        float* dst = out_lds + (e0 + er) * STRIDE + OOFF + o;
        if (COLS == 4) *(float4*)dst = make_float4(v[0], v[1], v[2], v[3]);
        else           *(float2*)dst = make_float2(v[0], v[1]);
    }
}

// Message MLP over compacted edges + atomic scatter into aggr[n_agents][128].
// 16 edges per tile, ~1024 tiles; grid 1024 => 4 blocks/CU (LDS 33KB).
#define ETE 16
__global__ __launch_bounds__(256, 4)
void edge_mlp(const float* __restrict__ x, const int2* __restrict__ edges,
              const int* __restrict__ counter, int cap, float* __restrict__ aggr,
              const float* __restrict__ Wm1, const float* __restrict__ bm1,
              const float* __restrict__ Wm2, const float* __restrict__ bm2,
              const float* __restrict__ Wm3, const float* __restrict__ bm3) {
    __shared__ float bufA[ETE * STRIDE];
    __shared__ float bufB[ETE * STRIDE];
    __shared__ int sL[ETE], rL[ETE];
    const int count = min(counter[0], cap);
    const int ntiles = (count + ETE - 1) / ETE;
    const int t = (int)threadIdx.x;
    for (int tile = (int)blockIdx.x; tile < ntiles; tile += (int)gridDim.x) {
        const int base = tile * ETE;
        if (t < ETE) {
            int eg = base + t;
            int2 ed = (eg < count) ? edges[eg] : make_int2(0, -1);
            sL[t] = ed.x; rL[t] = ed.y;
        }
        __syncthreads();
        // gather h0 = [x[sender] | x[receiver]] -> bufA[16][128], float4 loads
        {
            int slots = ETE * 128 / 4;              // 512 float4 slots
            for (int idx = t; idx < slots; idx += 256) {
                int e = idx >> 5;                   // 32 float4 per row
                int f4 = (idx & 31) * 4;
                int node = (f4 < 64) ? sL[e] : rL[e];
                float4 v = make_float4(0.f, 0.f, 0.f, 0.f);
                if (rL[e] >= 0) v = *(const float4*)(x + (size_t)node * 64 + (f4 & 63));
                *(float4*)(bufA + e * STRIDE + f4) = v;
            }
        }
        __syncthreads();
        mlp_layer<256, ETE, 128, 256, 4, 8, true,  0>(bufA, bufB, Wm1, bm1);
        __syncthreads();
        mlp_layer<256, ETE, 256, 256, 4, 8, true,  0>(bufB, bufA, Wm2, bm2);
        __syncthreads();
        mlp_layer<256, ETE, 256, 128, 4, 8, false, 0>(bufA, bufB, Wm3, bm3);
        __syncthreads();
        // scatter-add msg into aggr (device-scope fp32 atomics)
        for (int idx = t; idx < ETE * 128; idx += 256) {
            int e = idx >> 7, o = idx & 127;
            if (base + e < count) {
                atomicAdd(&aggr[(size_t)rL[e] * 128 + o], bufB[e * STRIDE + o]);
            }
        }
        __syncthreads();
    }
}

// Fused per-node pipeline for the first n_agents nodes:
// aggr -> aggMLP -> concat(x, a) -> updateMLP -> feats; actions -> proj;
// concat(feats, ap) -> headMLP -> q.  4 nodes per 256-thread block.
// Grid-bound at 1 block/CU -> VGPRs are free; launch_bounds(256,1).
#define NTE 4
__global__ __launch_bounds__(256, 1)
void node_update(const float* __restrict__ x, const float* __restrict__ actions,
                 const float* __restrict__ aggr, int n_agents,
                 const float* __restrict__ Wa1, const float* __restrict__ ba1,
                 const float* __restrict__ Wa2, const float* __restrict__ ba2,
                 const float* __restrict__ Wa3, const float* __restrict__ ba3,
                 const float* __restrict__ Wu1, const float* __restrict__ bu1,
                 const float* __restrict__ Wu2, const float* __restrict__ bu2,
                 const float* __restrict__ Wu3, const float* __restrict__ bu3,
                 const float* __restrict__ Wact, const float* __restrict__ bact,
                 const float* __restrict__ Wh1, const float* __restrict__ bh1,
                 const float* __restrict__ Wh2, const float* __restrict__ bh2,
                 const float* __restrict__ Wq,  const float* __restrict__ bq,
                 float* __restrict__ out) {
    __shared__ float bufA[NTE * STRIDE];
    __shared__ float bufB[NTE * STRIDE];
    const int t = (int)threadIdx.x;
    const int base = (int)blockIdx.x * NTE;

    // load aggr rows -> bufA[4][128] (float4)
    if (t < NTE * 128 / 4) {
        int e = t >> 5, f4 = (t & 31) * 4;
        int node = base + e;
        float4 v = make_float4(0.f, 0.f, 0.f, 0.f);
        if (node < n_agents) v = *(const float4*)(aggr + (size_t)node * 128 + f4);
        *(float4*)(bufA + e * STRIDE + f4) = v;
    }
    __syncthreads();
    mlp_layer<256, NTE, 128, 128, 2, 32, true,  0>(bufA, bufB, Wa1, ba1); __syncthreads();
    mlp_layer<256, NTE, 128, 128, 2, 32, true,  0>(bufB, bufA, Wa2, ba2); __syncthreads();
    mlp_layer<256, NTE, 128, 128, 2, 32, false, 0>(bufA, bufB, Wa3, ba3); __syncthreads();
    // u0 = [x(64) | a(128)] -> bufA width 192
    if (t < NTE * 64 / 4) {
        int e = t >> 4, f4 = (t & 15) * 4;
        int node = base + e;
        float4 v = make_float4(0.f, 0.f, 0.f, 0.f);
        if (node < n_agents) v = *(const float4*)(x + (size_t)node * 64 + f4);
        *(float4*)(bufA + e * STRIDE + f4) = v;
    }
    if (t < NTE * 128 / 4) {
        int e = t >> 5, f4 = (t & 31) * 4;
        *(float4*)(bufA + e * STRIDE + 64 + f4) = *(const float4*)(bufB + e * STRIDE + f4);
    }
    __syncthreads();
    mlp_layer<256, NTE, 192, 256, 4, 16, true,  0>(bufA, bufB, Wu1, bu1); __syncthreads();
    mlp_layer<256, NTE, 256, 256, 4, 16, true,  0>(bufB, bufA, Wu2, bu2); __syncthreads();
    mlp_layer<256, NTE, 256, 128, 2, 32, false, 0>(bufA, bufB, Wu3, bu3); __syncthreads();
    // feats now in bufB[:, 0:128]. Stage actions -> bufA[:, 0:16]
    if (t < NTE * 16 / 4) {
        int e = t >> 2, f4 = (t & 3) * 4;
        int node = base + e;
        float4 v = make_float4(0.f, 0.f, 0.f, 0.f);
        if (node < n_agents) v = *(const float4*)(actions + (size_t)node * 16 + f4);
        *(float4*)(bufA + e * STRIDE + f4) = v;
    }
    __syncthreads();
    // ap = relu(actions @ Wact) written into bufB[:, 128:256] => z in bufB
    mlp_layer<256, NTE, 16,  128, 2, 16, true, 128>(bufA, bufB, Wact, bact); __syncthreads();
    mlp_layer<256, NTE, 256, 256, 4, 16, true, 0>(bufB, bufA, Wh1, bh1); __syncthreads();
    mlp_layer<256, NTE, 256, 256, 4, 16, true, 0>(bufA, bufB, Wh2, bh2); __syncthreads();
    // q = z2 @ Wq + bq : one wave per node, lane l covers cols 4l..4l+3
    {
        int wv = t >> 6, lane = t & 63;
        int node = base + wv;
        float4 z = *(const float4*)(bufB + wv * STRIDE + lane * 4);
        float4 qw = *(const float4*)(Wq + lane * 4);
        float p = z.x * qw.x + z.y * qw.y + z.z * qw.z + z.w * qw.w;
#pragma unroll
        for (int off = 32; off >= 1; off >>= 1) p += __shfl_down(p, off, 64);
        if (lane == 0 && node < n_agents) out[node] = p + bq[0];
    }
}

extern "C" void kernel_launch(void* const* d_in, const int* in_sizes, int n_in,
                              void* d_out, int out_size, void* d_ws, size_t ws_size,
                              hipStream_t stream) {
    const float* x        = (const float*)d_in[0];
    const float* actions  = (const float*)d_in[1];
    const int*   senders  = (const int*)d_in[2];
    const int*   receivers= (const int*)d_in[3];
    // d_in[4] = n_agents (device scalar); host-side value == out_size
    const float* Wm1 = (const float*)d_in[5],  *bm1 = (const float*)d_in[6];
    const float* Wm2 = (const float*)d_in[7],  *bm2 = (const float*)d_in[8];
    const float* Wm3 = (const float*)d_in[9],  *bm3 = (const float*)d_in[10];
    const float* Wa1 = (const float*)d_in[11], *ba1 = (const float*)d_in[12];
    const float* Wa2 = (const float*)d_in[13], *ba2 = (const float*)d_in[14];
    const float* Wa3 = (const float*)d_in[15], *ba3 = (const float*)d_in[16];
    const float* Wu1 = (const float*)d_in[17], *bu1 = (const float*)d_in[18];
    const float* Wu2 = (const float*)d_in[19], *bu2 = (const float*)d_in[20];
    const float* Wu3 = (const float*)d_in[21], *bu3 = (const float*)d_in[22];
    const float* Wact= (const float*)d_in[23], *bact= (const float*)d_in[24];
    const float* Wh1 = (const float*)d_in[25], *bh1 = (const float*)d_in[26];
    const float* Wh2 = (const float*)d_in[27], *bh2 = (const float*)d_in[28];
    const float* Wq  = (const float*)d_in[29], *bq  = (const float*)d_in[30];

    const int E = in_sizes[2];
    const int n_agents = out_size;   // q has one entry per agent

    // workspace layout: [0..4) counter | [1024 ..) aggr | [edgeOff ..) edges
    char* ws = (char*)d_ws;
    int*   counter = (int*)ws;
    float* aggr    = (float*)(ws + 1024);
    size_t aggrBytes = (size_t)n_agents * 128 * sizeof(float);
    size_t edgeOff = 1024 + ((aggrBytes + 1023) / 1024) * 1024;
    int2*  edges   = (int2*)(ws + edgeOff);
    int cap = (int)((ws_size > edgeOff) ? (ws_size - edgeOff) / sizeof(int2) : 0);
    if (cap > E) cap = E;

    // zero counter + aggr (memset nodes are graph-capturable)
    hipMemsetAsync(ws, 0, edgeOff, stream);

    int fblocks = (E + FILT_CHUNK - 1) / FILT_CHUNK;
    filter_edges<<<fblocks, 256, 0, stream>>>(senders, receivers, E, n_agents,
                                              cap, counter, edges);

    edge_mlp<<<1024, 256, 0, stream>>>(x, edges, counter, cap, aggr,
                                       Wm1, bm1, Wm2, bm2, Wm3, bm3);

    node_update<<<(n_agents + NTE - 1) / NTE, 256, 0, stream>>>(
        x, actions, aggr, n_agents,
        Wa1, ba1, Wa2, ba2, Wa3, ba3,
        Wu1, bu1, Wu2, bu2, Wu3, bu3,
        Wact, bact, Wh1, bh1, Wh2, bh2, Wq, bq,
        (float*)d_out);
}

// Round 4
// 240.162 us; speedup vs baseline: 7.7311x; 7.7311x over previous
//
#include <hip/hip_runtime.h>

// ---------------------------------------------------------------------------
// CriticWithGNN: only nodes < n_agents reach the output, so only edges with
// receiver < n_agents (~2% of E) need the message MLP. FLOPs: 210G -> ~5G.
// R4: revert R3 spill-trap (NO runtime-indexed register arrays). k-split
// thread groups cut intra-block weight re-reads; ETE=32; ballot-filter.
// ---------------------------------------------------------------------------

#define STRIDE 260   // LDS row stride in words (mult of 4 for float4, 260%32=4)

// Compact edges with receiver < n_agents. Wave-ballot aggregation -> 1 LDS
// atomic per wave per iter; 1 global atomic per block.
#define FILT_CHUNK 4096
__global__ void filter_edges(const int* __restrict__ senders,
                             const int* __restrict__ receivers,
                             int E, int n_agents, int cap,
                             int* __restrict__ counter, int2* __restrict__ edges) {
    __shared__ int lcount;
    __shared__ int lbase;
    __shared__ int2 lbuf[FILT_CHUNK];
    const int t = (int)threadIdx.x;
    if (t == 0) lcount = 0;
    __syncthreads();
    int start = blockIdx.x * FILT_CHUNK;
    int end = min(start + FILT_CHUNK, E);
    for (int b0 = start; b0 < end; b0 += 256) {
        int idx = b0 + t;
        int r = -1, s = 0;
        bool pred = false;
        if (idx < end) {
            r = receivers[idx];
            pred = (r < n_agents);
            if (pred) s = senders[idx];
        }
        unsigned long long m = __ballot(pred);
        int lane = t & 63;
        int below = __popcll(m & ((1ull << lane) - 1));
        int cnt = __popcll(m);
        int wbase = 0;
        if (lane == 0 && cnt) wbase = atomicAdd(&lcount, cnt);
        wbase = __shfl(wbase, 0, 64);
        if (pred) lbuf[wbase + below] = make_int2(s, r);
    }
    __syncthreads();
    if (t == 0) lbase = atomicAdd(counter, lcount);
    __syncthreads();
    for (int i = t; i < lcount; i += 256) {
        int pos = lbase + i;
        if (pos < cap) edges[pos] = lbuf[i];
    }
}

// Dense layer on an LDS tile: out[TE][NOUT] = act(in[TE][NIN] @ W + b).
// 256 threads split as TX col-threads (COLS cols each) x KS k-splits x RG
// row-groups. k-splitting means W is read RG (not NG) times per block.
// KS>1: groups ks>=1 write raw partials (ks==1 into out_lds itself at the
// final addresses -- one writer then one reader/writer per word, race-free;
// ks>=2 into part_lds regions); barrier; ks==0 reduces + bias + act + store.
// All locals statically indexed under full unrolls (R3 spill-trap avoided).
template<int TE, int NIN, int NOUT, int COLS, int KS, bool RELU, int OOFF, int UNR>
__device__ __forceinline__ void mlp_layer(const float* in_lds, float* out_lds,
                                          float* part_lds,
                                          const float* __restrict__ W,
                                          const float* __restrict__ b) {
    constexpr int TX = NOUT / COLS;
    constexpr int NG = 256 / TX;
    static_assert(NG % KS == 0, "k-splits divide groups");
    constexpr int RG = NG / KS;
    static_assert(TE % RG == 0, "rows divide row-groups");
    constexpr int ER = TE / RG;
    constexpr int KRANGE = NIN / KS;
    static_assert(KRANGE % 4 == 0, "k-range multiple of 4");

    const int t   = (int)threadIdx.x;
    const int tx  = t % TX;
    const int grp = t / TX;
    const int ks  = grp % KS;
    const int rg  = grp / KS;
    const int o   = tx * COLS;
    const int e0  = rg * ER;
    const int k0  = ks * KRANGE;

    float acc[ER][COLS];
#pragma unroll
    for (int er = 0; er < ER; ++er)
#pragma unroll
        for (int c = 0; c < COLS; ++c) acc[er][c] = 0.f;

#pragma unroll UNR
    for (int kb = 0; kb < KRANGE; kb += 4) {
        const int k = k0 + kb;
        float w[4][COLS];
#pragma unroll
        for (int j = 0; j < 4; ++j) {
            const float* wp = W + (size_t)(k + j) * NOUT + o;
            if (COLS == 4) {
                float4 v = *(const float4*)wp;
                w[j][0] = v.x; w[j][1] = v.y; w[j][2] = v.z; w[j][3] = v.w;
            } else {
                float2 v = *(const float2*)wp;
                w[j][0] = v.x; w[j][1] = v.y;
            }
        }
#pragma unroll
        for (int er = 0; er < ER; ++er) {
            float4 a = *(const float4*)(in_lds + (e0 + er) * STRIDE + k);
#pragma unroll
            for (int c = 0; c < COLS; ++c) {
                acc[er][c] += a.x * w[0][c] + a.y * w[1][c]
                            + a.z * w[2][c] + a.w * w[3][c];
            }
        }
    }

    if (KS == 1) {
#pragma unroll
        for (int er = 0; er < ER; ++er) {
            float v[COLS];
#pragma unroll
            for (int c = 0; c < COLS; ++c) {
                v[c] = acc[er][c] + b[o + c];
                if (RELU) v[c] = fmaxf(v[c], 0.f);
            }
            float* dst = out_lds + (e0 + er) * STRIDE + OOFF + o;
            if (COLS == 4) *(float4*)dst = make_float4(v[0], v[1], v[2], v[3]);
            else           *(float2*)dst = make_float2(v[0], v[1]);
        }
    } else {
        if (ks != 0) {
            float* pr = (ks == 1) ? out_lds : part_lds + (size_t)(ks - 2) * TE * STRIDE;
#pragma unroll
            for (int er = 0; er < ER; ++er) {
                float* dst = pr + (e0 + er) * STRIDE + OOFF + o;
                if (COLS == 4) *(float4*)dst = make_float4(acc[er][0], acc[er][1],
                                                           acc[er][2], acc[er][3]);
                else           *(float2*)dst = make_float2(acc[er][0], acc[er][1]);
            }
        }
        __syncthreads();
        if (ks == 0) {
#pragma unroll
            for (int er = 0; er < ER; ++er) {
                float v[COLS];
#pragma unroll
                for (int c = 0; c < COLS; ++c) v[c] = acc[er][c];
#pragma unroll
                for (int j = 1; j < KS; ++j) {
                    const float* pr = (j == 1) ? out_lds
                                               : part_lds + (size_t)(j - 2) * TE * STRIDE;
                    const float* src = pr + (e0 + er) * STRIDE + OOFF + o;
                    if (COLS == 4) {
                        float4 p = *(const float4*)src;
                        v[0] += p.x; v[1] += p.y; v[2] += p.z; v[3] += p.w;
                    } else {
                        float2 p = *(const float2*)src;
                        v[0] += p.x; v[1] += p.y;
                    }
                }
#pragma unroll
                for (int c = 0; c < COLS; ++c) {
                    v[c] += b[o + c];
                    if (RELU) v[c] = fmaxf(v[c], 0.f);
                }
                float* dst = out_lds + (e0 + er) * STRIDE + OOFF + o;
                if (COLS == 4) *(float4*)dst = make_float4(v[0], v[1], v[2], v[3]);
                else           *(float2*)dst = make_float2(v[0], v[1]);
            }
        }
    }
}

// Message MLP over compacted edges + atomic scatter into aggr[n_agents][128].
// 32 edges per tile (~512 tiles), grid 512 => 2 blocks/CU (67KB LDS each).
#define ETE 32
__global__ __launch_bounds__(256, 2)
void edge_mlp(const float* __restrict__ x, const int2* __restrict__ edges,
              const int* __restrict__ counter, int cap, float* __restrict__ aggr,
              const float* __restrict__ Wm1, const float* __restrict__ bm1,
              const float* __restrict__ Wm2, const float* __restrict__ bm2,
              const float* __restrict__ Wm3, const float* __restrict__ bm3) {
    __shared__ float bufA[ETE * STRIDE];
    __shared__ float bufB[ETE * STRIDE];
    __shared__ int sL[ETE], rL[ETE];
    const int count = min(counter[0], cap);
    const int ntiles = (count + ETE - 1) / ETE;
    const int t = (int)threadIdx.x;
    for (int tile = (int)blockIdx.x; tile < ntiles; tile += (int)gridDim.x) {
        const int base = tile * ETE;
        if (t < ETE) {
            int eg = base + t;
            int2 ed = (eg < count) ? edges[eg] : make_int2(0, -1);
            sL[t] = ed.x; rL[t] = ed.y;
        }
        __syncthreads();
        // gather h0 = [x[sender] | x[receiver]] -> bufA[32][128], float4 loads
        for (int idx = t; idx < ETE * 32; idx += 256) {
            int e = idx >> 5;                   // 32 float4 per row
            int f4 = (idx & 31) * 4;
            int node = (f4 < 64) ? sL[e] : rL[e];
            float4 v = make_float4(0.f, 0.f, 0.f, 0.f);
            if (rL[e] >= 0) v = *(const float4*)(x + (size_t)node * 64 + (f4 & 63));
            *(float4*)(bufA + e * STRIDE + f4) = v;
        }
        __syncthreads();
        mlp_layer<ETE, 128, 256, 4, 2, true,  0, 2>(bufA, bufB, nullptr, Wm1, bm1);
        __syncthreads();
        mlp_layer<ETE, 256, 256, 4, 2, true,  0, 2>(bufB, bufA, nullptr, Wm2, bm2);
        __syncthreads();
        mlp_layer<ETE, 256, 128, 4, 2, false, 0, 2>(bufA, bufB, nullptr, Wm3, bm3);
        __syncthreads();
        // scatter-add msg into aggr (device-scope fp32 atomics)
        for (int idx = t; idx < ETE * 128; idx += 256) {
            int e = idx >> 7, o = idx & 127;
            if (base + e < count) {
                atomicAdd(&aggr[(size_t)rL[e] * 128 + o], bufB[e * STRIDE + o]);
            }
        }
        __syncthreads();
    }
}

// Fused per-node pipeline for the first n_agents nodes. 4 nodes per block.
// KS=4 k-splits: W read once per block, short fully-unrolled k-loops for ILP.
#define NTE 4
__global__ __launch_bounds__(256, 1)
void node_update(const float* __restrict__ x, const float* __restrict__ actions,
                 const float* __restrict__ aggr, int n_agents,
                 const float* __restrict__ Wa1, const float* __restrict__ ba1,
                 const float* __restrict__ Wa2, const float* __restrict__ ba2,
                 const float* __restrict__ Wa3, const float* __restrict__ ba3,
                 const float* __restrict__ Wu1, const float* __restrict__ bu1,
                 const float* __restrict__ Wu2, const float* __restrict__ bu2,
                 const float* __restrict__ Wu3, const float* __restrict__ bu3,
                 const float* __restrict__ Wact, const float* __restrict__ bact,
                 const float* __restrict__ Wh1, const float* __restrict__ bh1,
                 const float* __restrict__ Wh2, const float* __restrict__ bh2,
                 const float* __restrict__ Wq,  const float* __restrict__ bq,
                 float* __restrict__ out) {
    __shared__ float bufA[NTE * STRIDE];
    __shared__ float bufB[NTE * STRIDE];
    __shared__ float bufP[2 * NTE * STRIDE];   // partial regions for KS=4
    const int t = (int)threadIdx.x;
    const int base = (int)blockIdx.x * NTE;

    // load aggr rows -> bufA[4][128] (float4)
    if (t < NTE * 32) {
        int e = t >> 5, f4 = (t & 31) * 4;
        int node = base + e;
        float4 v = make_float4(0.f, 0.f, 0.f, 0.f);
        if (node < n_agents) v = *(const float4*)(aggr + (size_t)node * 128 + f4);
        *(float4*)(bufA + e * STRIDE + f4) = v;
    }
    __syncthreads();
    mlp_layer<NTE, 128, 128, 2, 4, true,  0, 8>(bufA, bufB, bufP, Wa1, ba1); __syncthreads();
    mlp_layer<NTE, 128, 128, 2, 4, true,  0, 8>(bufB, bufA, bufP, Wa2, ba2); __syncthreads();
    mlp_layer<NTE, 128, 128, 2, 4, false, 0, 8>(bufA, bufB, bufP, Wa3, ba3); __syncthreads();
    // u0 = [x(64) | a(128)] -> bufA width 192
    if (t < NTE * 16) {
        int e = t >> 4, f4 = (t & 15) * 4;
        int node = base + e;
        float4 v = make_float4(0.f, 0.f, 0.f, 0.f);
        if (node < n_agents) v = *(const float4*)(x + (size_t)node * 64 + f4);
        *(float4*)(bufA + e * STRIDE + f4) = v;
    }
    if (t < NTE * 32) {
        int e = t >> 5, f4 = (t & 31) * 4;
        *(float4*)(bufA + e * STRIDE + 64 + f4) = *(const float4*)(bufB + e * STRIDE + f4);
    }
    __syncthreads();
    mlp_layer<NTE, 192, 256, 4, 4, true,  0, 4>(bufA, bufB, bufP, Wu1, bu1); __syncthreads();
    mlp_layer<NTE, 256, 256, 4, 4, true,  0, 4>(bufB, bufA, bufP, Wu2, bu2); __syncthreads();
    mlp_layer<NTE, 256, 128, 2, 4, false, 0, 4>(bufA, bufB, bufP, Wu3, bu3); __syncthreads();
    // feats now in bufB[:, 0:128]. Stage actions -> bufA[:, 0:16]
    if (t < NTE * 4) {
        int e = t >> 2, f4 = (t & 3) * 4;
        int node = base + e;
        float4 v = make_float4(0.f, 0.f, 0.f, 0.f);
        if (node < n_agents) v = *(const float4*)(actions + (size_t)node * 16 + f4);
        *(float4*)(bufA + e * STRIDE + f4) = v;
    }
    __syncthreads();
    // ap = relu(actions @ Wact) into bufB[:, 128:256] => z in bufB
    mlp_layer<NTE, 16,  128, 2, 4, true, 128, 1>(bufA, bufB, bufP, Wact, bact); __syncthreads();
    mlp_layer<NTE, 256, 256, 4, 4, true, 0,   4>(bufB, bufA, bufP, Wh1, bh1); __syncthreads();
    mlp_layer<NTE, 256, 256, 4, 4, true, 0,   4>(bufA, bufB, bufP, Wh2, bh2); __syncthreads();
    // q = z2 @ Wq + bq : one wave per node, lane l covers cols 4l..4l+3
    {
        int wv = t >> 6, lane = t & 63;
        int node = base + wv;
        float4 z = *(const float4*)(bufB + wv * STRIDE + lane * 4);
        float4 qw = *(const float4*)(Wq + lane * 4);
        float p = z.x * qw.x + z.y * qw.y + z.z * qw.z + z.w * qw.w;
#pragma unroll
        for (int off = 32; off >= 1; off >>= 1) p += __shfl_down(p, off, 64);
        if (lane == 0 && node < n_agents) out[node] = p + bq[0];
    }
}

extern "C" void kernel_launch(void* const* d_in, const int* in_sizes, int n_in,
                              void* d_out, int out_size, void* d_ws, size_t ws_size,
                              hipStream_t stream) {
    const float* x        = (const float*)d_in[0];
    const float* actions  = (const float*)d_in[1];
    const int*   senders  = (const int*)d_in[2];
    const int*   receivers= (const int*)d_in[3];
    // d_in[4] = n_agents (device scalar); host-side value == out_size
    const float* Wm1 = (const float*)d_in[5],  *bm1 = (const float*)d_in[6];
    const float* Wm2 = (const float*)d_in[7],  *bm2 = (const float*)d_in[8];
    const float* Wm3 = (const float*)d_in[9],  *bm3 = (const float*)d_in[10];
    const float* Wa1 = (const float*)d_in[11], *ba1 = (const float*)d_in[12];
    const float* Wa2 = (const float*)d_in[13], *ba2 = (const float*)d_in[14];
    const float* Wa3 = (const float*)d_in[15], *ba3 = (const float*)d_in[16];
    const float* Wu1 = (const float*)d_in[17], *bu1 = (const float*)d_in[18];
    const float* Wu2 = (const float*)d_in[19], *bu2 = (const float*)d_in[20];
    const float* Wu3 = (const float*)d_in[21], *bu3 = (const float*)d_in[22];
    const float* Wact= (const float*)d_in[23], *bact= (const float*)d_in[24];
    const float* Wh1 = (const float*)d_in[25], *bh1 = (const float*)d_in[26];
    const float* Wh2 = (const float*)d_in[27], *bh2 = (const float*)d_in[28];
    const float* Wq  = (const float*)d_in[29], *bq  = (const float*)d_in[30];

    const int E = in_sizes[2];
    const int n_agents = out_size;   // q has one entry per agent

    // workspace layout: [0..4) counter | [1024 ..) aggr | [edgeOff ..) edges
    char* ws = (char*)d_ws;
    int*   counter = (int*)ws;
    float* aggr    = (float*)(ws + 1024);
    size_t aggrBytes = (size_t)n_agents * 128 * sizeof(float);
    size_t edgeOff = 1024 + ((aggrBytes + 1023) / 1024) * 1024;
    int2*  edges   = (int2*)(ws + edgeOff);
    int cap = (int)((ws_size > edgeOff) ? (ws_size - edgeOff) / sizeof(int2) : 0);
    if (cap > E) cap = E;

    // zero counter + aggr (memset nodes are graph-capturable)
    hipMemsetAsync(ws, 0, edgeOff, stream);

    int fblocks = (E + FILT_CHUNK - 1) / FILT_CHUNK;
    filter_edges<<<fblocks, 256, 0, stream>>>(senders, receivers, E, n_agents,
                                              cap, counter, edges);

    edge_mlp<<<512, 256, 0, stream>>>(x, edges, counter, cap, aggr,
                                      Wm1, bm1, Wm2, bm2, Wm3, bm3);

    node_update<<<(n_agents + NTE - 1) / NTE, 256, 0, stream>>>(
        x, actions, aggr, n_agents,
        Wa1, ba1, Wa2, ba2, Wa3, ba3,
        Wu1, bu1, Wu2, bu2, Wu3, bu3,
        Wact, bact, Wh1, bh1, Wh2, bh2, Wq, bq,
        (float*)d_out);
}

// Round 5
// 198.501 us; speedup vs baseline: 9.3537x; 1.2099x over previous
//
#include <hip/hip_runtime.h>
#include <hip/hip_bf16.h>

// ---------------------------------------------------------------------------
// CriticWithGNN: only nodes < n_agents reach the output, so only edges with
// receiver < n_agents (~2% of E) need the message MLP. FLOPs: 210G -> ~5G.
// R5: edge MLP on MFMA with SPLIT-PRECISION bf16 (hi=trunc, lo=residual;
// A*W ~= Ahi*Whi + Ahi*Wlo + Alo*Whi -> ~2^-17 rel err, fp32-grade) — weights
// pre-packed per launch into B-fragment layout in ws. node_update stays fp32.
// ---------------------------------------------------------------------------

#define STRIDE 260   // LDS row stride in words (mult of 4 for float4, 260%32=4)

typedef __attribute__((ext_vector_type(8))) short short8;
typedef __attribute__((ext_vector_type(4))) float floatx4;

union Frag8 { short8 s; uint u[4]; };

// hi = truncate-to-bf16 (mask), lo = RNE-bf16(f - hi)  [exact residual]
__device__ __forceinline__ void cvt_hi_lo(const float4 f0, const float4 f1,
                                          Frag8& hi, Frag8& lo) {
    uint U[8] = { __float_as_uint(f0.x), __float_as_uint(f0.y),
                  __float_as_uint(f0.z), __float_as_uint(f0.w),
                  __float_as_uint(f1.x), __float_as_uint(f1.y),
                  __float_as_uint(f1.z), __float_as_uint(f1.w) };
    float F[8] = { f0.x, f0.y, f0.z, f0.w, f1.x, f1.y, f1.z, f1.w };
#pragma unroll
    for (int p = 0; p < 4; ++p) {
        uint a = U[2*p], b = U[2*p+1];
        hi.u[p] = (a >> 16) | (b & 0xFFFF0000u);
        float l0 = F[2*p]   - __uint_as_float(a & 0xFFFF0000u);
        float l1 = F[2*p+1] - __uint_as_float(b & 0xFFFF0000u);
        __hip_bfloat162 pl = __float22bfloat162_rn(make_float2(l0, l1));
        union { __hip_bfloat162 h; uint v; } cvt; cvt.h = pl;
        lo.u[p] = cvt.v;
    }
}

// ---------------- weight pre-pack (runs every launch; ws re-poisoned) ------
// Packs Wm1/Wm2/Wm3 (fp32 row-major [NIN][NOUT]) into MFMA B-frag layout:
// entry ((kb*NT + nt)*64 + lane) = 8 bf16 covering k=kb*32+quad*8+j, n=nt*16+l15.
// hi (trunc) and lo (residual) regions. uint offsets within pack region:
//  L1hi 0 | L1lo 16384 | L2hi 32768 | L2lo 65536 | L3hi 98304 | L3lo 114688
__global__ void pack_weights(const float* __restrict__ Wm1,
                             const float* __restrict__ Wm2,
                             const float* __restrict__ Wm3,
                             uint* __restrict__ pack) {
    int g = blockIdx.x * 256 + threadIdx.x;      // 16384 total
    const float* W; int NOUT, NT, local; uint *dhi, *dlo;
    if (g < 4096)       { W = Wm1; NOUT = 256; NT = 16; local = g;         dhi = pack;          dlo = pack + 16384; }
    else if (g < 12288) { W = Wm2; NOUT = 256; NT = 16; local = g - 4096;  dhi = pack + 32768;  dlo = pack + 65536; }
    else                { W = Wm3; NOUT = 128; NT = 8;  local = g - 12288; dhi = pack + 98304;  dlo = pack + 114688; }
    int lane = local & 63;
    int tmp  = local >> 6;
    int nt = tmp % NT, kb = tmp / NT;
    int n  = nt * 16 + (lane & 15);
    int k0 = kb * 32 + ((lane >> 4) & 3) * 8;
    uint hi[4], lo[4];
#pragma unroll
    for (int p = 0; p < 4; ++p) {
        float f0 = W[(size_t)(k0 + 2*p)     * NOUT + n];
        float f1 = W[(size_t)(k0 + 2*p + 1) * NOUT + n];
        uint U0 = __float_as_uint(f0), U1 = __float_as_uint(f1);
        hi[p] = (U0 >> 16) | (U1 & 0xFFFF0000u);
        float l0 = f0 - __uint_as_float(U0 & 0xFFFF0000u);
        float l1 = f1 - __uint_as_float(U1 & 0xFFFF0000u);
        __hip_bfloat162 pl = __float22bfloat162_rn(make_float2(l0, l1));
        union { __hip_bfloat162 h; uint v; } cvt; cvt.h = pl;
        lo[p] = cvt.v;
    }
    int idx = ((kb * NT + nt) * 64 + lane) * 4;
    *(uint4*)(dhi + idx) = make_uint4(hi[0], hi[1], hi[2], hi[3]);
    *(uint4*)(dlo + idx) = make_uint4(lo[0], lo[1], lo[2], lo[3]);
}

// Compact edges with receiver < n_agents. Wave-ballot aggregation.
#define FILT_CHUNK 4096
__global__ void filter_edges(const int* __restrict__ senders,
                             const int* __restrict__ receivers,
                             int E, int n_agents, int cap,
                             int* __restrict__ counter, int2* __restrict__ edges) {
    __shared__ int lcount;
    __shared__ int lbase;
    __shared__ int2 lbuf[FILT_CHUNK];
    const int t = (int)threadIdx.x;
    if (t == 0) lcount = 0;
    __syncthreads();
    int start = blockIdx.x * FILT_CHUNK;
    int end = min(start + FILT_CHUNK, E);
    for (int b0 = start; b0 < end; b0 += 256) {
        int idx = b0 + t;
        int r = -1, s = 0;
        bool pred = false;
        if (idx < end) {
            r = receivers[idx];
            pred = (r < n_agents);
            if (pred) s = senders[idx];
        }
        unsigned long long m = __ballot(pred);
        int lane = t & 63;
        int below = __popcll(m & ((1ull << lane) - 1));
        int cnt = __popcll(m);
        int wbase = 0;
        if (lane == 0 && cnt) wbase = atomicAdd(&lcount, cnt);
        wbase = __shfl(wbase, 0, 64);
        if (pred) lbuf[wbase + below] = make_int2(s, r);
    }
    __syncthreads();
    if (t == 0) lbase = atomicAdd(counter, lcount);
    __syncthreads();
    for (int i = t; i < lcount; i += 256) {
        int pos = lbase + i;
        if (pos < cap) edges[pos] = lbuf[i];
    }
}

// ------------- MFMA dense layer on a 32-row LDS tile -----------------------
// out[32][NOUT] = act(in[32][NIN] @ W + b); 4 waves, each owns NOUT/64 cols.
// A-frags built from fp32 LDS (hi/lo split); B-frags are pre-packed 16B loads.
// C/D layout (verified m89): col=lane&15, row=quad*4+reg.
template<int NIN, int NOUT, bool RELU>
__device__ __forceinline__ void mfma_layer(const float* in_lds, float* out_lds,
                                           const uint4* __restrict__ Whi,
                                           const uint4* __restrict__ Wlo,
                                           const float* __restrict__ b) {
    constexpr int KB  = NIN / 32;
    constexpr int NT  = NOUT / 16;
    constexpr int NTW = NT / 4;
    const int t    = (int)threadIdx.x;
    const int wave = t >> 6;
    const int l15  = t & 15;
    const int quad = (t >> 4) & 3;

    floatx4 acc[2][NTW];
#pragma unroll
    for (int mt = 0; mt < 2; ++mt)
#pragma unroll
        for (int i = 0; i < NTW; ++i) acc[mt][i] = (floatx4){0.f, 0.f, 0.f, 0.f};

#pragma unroll 2
    for (int kb = 0; kb < KB; ++kb) {
        Frag8 ahi[2], alo[2];
#pragma unroll
        for (int mt = 0; mt < 2; ++mt) {
            const float* src = in_lds + (mt * 16 + l15) * STRIDE + kb * 32 + quad * 8;
            float4 f0 = *(const float4*)src;
            float4 f1 = *(const float4*)(src + 4);
            cvt_hi_lo(f0, f1, ahi[mt], alo[mt]);
        }
#pragma unroll
        for (int i = 0; i < NTW; ++i) {
            int nt = wave * NTW + i;
            int widx = (kb * NT + nt) * 64 + (t & 63);
            Frag8 bhi, blo;
            *(uint4*)bhi.u = Whi[widx];
            *(uint4*)blo.u = Wlo[widx];
#pragma unroll
            for (int mt = 0; mt < 2; ++mt) {
                acc[mt][i] = __builtin_amdgcn_mfma_f32_16x16x32_bf16(alo[mt].s, bhi.s, acc[mt][i], 0, 0, 0);
                acc[mt][i] = __builtin_amdgcn_mfma_f32_16x16x32_bf16(ahi[mt].s, blo.s, acc[mt][i], 0, 0, 0);
                acc[mt][i] = __builtin_amdgcn_mfma_f32_16x16x32_bf16(ahi[mt].s, bhi.s, acc[mt][i], 0, 0, 0);
            }
        }
    }
#pragma unroll
    for (int i = 0; i < NTW; ++i) {
        int n = (wave * NTW + i) * 16 + l15;
        float bias = b[n];
#pragma unroll
        for (int mt = 0; mt < 2; ++mt) {
#pragma unroll
            for (int r = 0; r < 4; ++r) {
                float v = acc[mt][i][r] + bias;
                if (RELU) v = fmaxf(v, 0.f);
                out_lds[(mt * 16 + quad * 4 + r) * STRIDE + n] = v;
            }
        }
    }
}

// Message MLP over compacted edges + atomic scatter into aggr[n_agents][128].
// 32 edges per tile (~512 tiles), grid 512 => 2 blocks/CU (67KB LDS each).
#define ETE 32
__global__ __launch_bounds__(256, 2)
void edge_mlp(const float* __restrict__ x, const int2* __restrict__ edges,
              const int* __restrict__ counter, int cap, float* __restrict__ aggr,
              const uint* __restrict__ pack,
              const float* __restrict__ bm1, const float* __restrict__ bm2,
              const float* __restrict__ bm3) {
    __shared__ float bufA[ETE * STRIDE];
    __shared__ float bufB[ETE * STRIDE];
    __shared__ int sL[ETE], rL[ETE];
    const uint4* W1hi = (const uint4*)(pack);
    const uint4* W1lo = (const uint4*)(pack + 16384);
    const uint4* W2hi = (const uint4*)(pack + 32768);
    const uint4* W2lo = (const uint4*)(pack + 65536);
    const uint4* W3hi = (const uint4*)(pack + 98304);
    const uint4* W3lo = (const uint4*)(pack + 114688);
    const int count = min(counter[0], cap);
    const int ntiles = (count + ETE - 1) / ETE;
    const int t = (int)threadIdx.x;
    for (int tile = (int)blockIdx.x; tile < ntiles; tile += (int)gridDim.x) {
        const int base = tile * ETE;
        if (t < ETE) {
            int eg = base + t;
            int2 ed = (eg < count) ? edges[eg] : make_int2(0, -1);
            sL[t] = ed.x; rL[t] = ed.y;
        }
        __syncthreads();
        // gather h0 = [x[sender] | x[receiver]] -> bufA[32][128], float4 loads
        for (int idx = t; idx < ETE * 32; idx += 256) {
            int e = idx >> 5;
            int f4 = (idx & 31) * 4;
            int node = (f4 < 64) ? sL[e] : rL[e];
            float4 v = make_float4(0.f, 0.f, 0.f, 0.f);
            if (rL[e] >= 0) v = *(const float4*)(x + (size_t)node * 64 + (f4 & 63));
            *(float4*)(bufA + e * STRIDE + f4) = v;
        }
        __syncthreads();
        mfma_layer<128, 256, true >(bufA, bufB, W1hi, W1lo, bm1);
        __syncthreads();
        mfma_layer<256, 256, true >(bufB, bufA, W2hi, W2lo, bm2);
        __syncthreads();
        mfma_layer<256, 128, false>(bufA, bufB, W3hi, W3lo, bm3);
        __syncthreads();
        // scatter-add msg into aggr (device-scope fp32 atomics)
        for (int idx = t; idx < ETE * 128; idx += 256) {
            int e = idx >> 7, o = idx & 127;
            if (base + e < count) {
                atomicAdd(&aggr[(size_t)rL[e] * 128 + o], bufB[e * STRIDE + o]);
            }
        }
        __syncthreads();
    }
}

// ---------------- fp32 k-split layer (node pipeline, unchanged R4) ---------
template<int TE, int NIN, int NOUT, int COLS, int KS, bool RELU, int OOFF, int UNR>
__device__ __forceinline__ void mlp_layer(const float* in_lds, float* out_lds,
                                          float* part_lds,
                                          const float* __restrict__ W,
                                          const float* __restrict__ b) {
    constexpr int TX = NOUT / COLS;
    constexpr int NG = 256 / TX;
    static_assert(NG % KS == 0, "k-splits divide groups");
    constexpr int RG = NG / KS;
    static_assert(TE % RG == 0, "rows divide row-groups");
    constexpr int ER = TE / RG;
    constexpr int KRANGE = NIN / KS;
    static_assert(KRANGE % 4 == 0, "k-range multiple of 4");

    const int t   = (int)threadIdx.x;
    const int tx  = t % TX;
    const int grp = t / TX;
    const int ks  = grp % KS;
    const int rg  = grp / KS;
    const int o   = tx * COLS;
    const int e0  = rg * ER;
    const int k0  = ks * KRANGE;

    float acc[ER][COLS];
#pragma unroll
    for (int er = 0; er < ER; ++er)
#pragma unroll
        for (int c = 0; c < COLS; ++c) acc[er][c] = 0.f;

#pragma unroll UNR
    for (int kb = 0; kb < KRANGE; kb += 4) {
        const int k = k0 + kb;
        float w[4][COLS];
#pragma unroll
        for (int j = 0; j < 4; ++j) {
            const float* wp = W + (size_t)(k + j) * NOUT + o;
            if (COLS == 4) {
                float4 v = *(const float4*)wp;
                w[j][0] = v.x; w[j][1] = v.y; w[j][2] = v.z; w[j][3] = v.w;
            } else {
                float2 v = *(const float2*)wp;
                w[j][0] = v.x; w[j][1] = v.y;
            }
        }
#pragma unroll
        for (int er = 0; er < ER; ++er) {
            float4 a = *(const float4*)(in_lds + (e0 + er) * STRIDE + k);
#pragma unroll
            for (int c = 0; c < COLS; ++c) {
                acc[er][c] += a.x * w[0][c] + a.y * w[1][c]
                            + a.z * w[2][c] + a.w * w[3][c];
            }
        }
    }

    if (KS == 1) {
#pragma unroll
        for (int er = 0; er < ER; ++er) {
            float v[COLS];
#pragma unroll
            for (int c = 0; c < COLS; ++c) {
                v[c] = acc[er][c] + b[o + c];
                if (RELU) v[c] = fmaxf(v[c], 0.f);
            }
            float* dst = out_lds + (e0 + er) * STRIDE + OOFF + o;
            if (COLS == 4) *(float4*)dst = make_float4(v[0], v[1], v[2], v[3]);
            else           *(float2*)dst = make_float2(v[0], v[1]);
        }
    } else {
        if (ks != 0) {
            float* pr = (ks == 1) ? out_lds : part_lds + (size_t)(ks - 2) * TE * STRIDE;
#pragma unroll
            for (int er = 0; er < ER; ++er) {
                float* dst = pr + (e0 + er) * STRIDE + OOFF + o;
                if (COLS == 4) *(float4*)dst = make_float4(acc[er][0], acc[er][1],
                                                           acc[er][2], acc[er][3]);
                else           *(float2*)dst = make_float2(acc[er][0], acc[er][1]);
            }
        }
        __syncthreads();
        if (ks == 0) {
#pragma unroll
            for (int er = 0; er < ER; ++er) {
                float v[COLS];
#pragma unroll
                for (int c = 0; c < COLS; ++c) v[c] = acc[er][c];
#pragma unroll
                for (int j = 1; j < KS; ++j) {
                    const float* pr = (j == 1) ? out_lds
                                               : part_lds + (size_t)(j - 2) * TE * STRIDE;
                    const float* src = pr + (e0 + er) * STRIDE + OOFF + o;
                    if (COLS == 4) {
                        float4 p = *(const float4*)src;
                        v[0] += p.x; v[1] += p.y; v[2] += p.z; v[3] += p.w;
                    } else {
                        float2 p = *(const float2*)src;
                        v[0] += p.x; v[1] += p.y;
                    }
                }
#pragma unroll
                for (int c = 0; c < COLS; ++c) {
                    v[c] += b[o + c];
                    if (RELU) v[c] = fmaxf(v[c], 0.f);
                }
                float* dst = out_lds + (e0 + er) * STRIDE + OOFF + o;
                if (COLS == 4) *(float4*)dst = make_float4(v[0], v[1], v[2], v[3]);
                else           *(float2*)dst = make_float2(v[0], v[1]);
            }
        }
    }
}

// Fused per-node pipeline for the first n_agents nodes. 4 nodes per block.
#define NTE 4
__global__ __launch_bounds__(256, 1)
void node_update(const float* __restrict__ x, const float* __restrict__ actions,
                 const float* __restrict__ aggr, int n_agents,
                 const float* __restrict__ Wa1, const float* __restrict__ ba1,
                 const float* __restrict__ Wa2, const float* __restrict__ ba2,
                 const float* __restrict__ Wa3, const float* __restrict__ ba3,
                 const float* __restrict__ Wu1, const float* __restrict__ bu1,
                 const float* __restrict__ Wu2, const float* __restrict__ bu2,
                 const float* __restrict__ Wu3, const float* __restrict__ bu3,
                 const float* __restrict__ Wact, const float* __restrict__ bact,
                 const float* __restrict__ Wh1, const float* __restrict__ bh1,
                 const float* __restrict__ Wh2, const float* __restrict__ bh2,
                 const float* __restrict__ Wq,  const float* __restrict__ bq,
                 float* __restrict__ out) {
    __shared__ float bufA[NTE * STRIDE];
    __shared__ float bufB[NTE * STRIDE];
    __shared__ float bufP[2 * NTE * STRIDE];   // partial regions for KS=4
    const int t = (int)threadIdx.x;
    const int base = (int)blockIdx.x * NTE;

    if (t < NTE * 32) {
        int e = t >> 5, f4 = (t & 31) * 4;
        int node = base + e;
        float4 v = make_float4(0.f, 0.f, 0.f, 0.f);
        if (node < n_agents) v = *(const float4*)(aggr + (size_t)node * 128 + f4);
        *(float4*)(bufA + e * STRIDE + f4) = v;
    }
    __syncthreads();
    mlp_layer<NTE, 128, 128, 2, 4, true,  0, 8>(bufA, bufB, bufP, Wa1, ba1); __syncthreads();
    mlp_layer<NTE, 128, 128, 2, 4, true,  0, 8>(bufB, bufA, bufP, Wa2, ba2); __syncthreads();
    mlp_layer<NTE, 128, 128, 2, 4, false, 0, 8>(bufA, bufB, bufP, Wa3, ba3); __syncthreads();
    if (t < NTE * 16) {
        int e = t >> 4, f4 = (t & 15) * 4;
        int node = base + e;
        float4 v = make_float4(0.f, 0.f, 0.f, 0.f);
        if (node < n_agents) v = *(const float4*)(x + (size_t)node * 64 + f4);
        *(float4*)(bufA + e * STRIDE + f4) = v;
    }
    if (t < NTE * 32) {
        int e = t >> 5, f4 = (t & 31) * 4;
        *(float4*)(bufA + e * STRIDE + 64 + f4) = *(const float4*)(bufB + e * STRIDE + f4);
    }
    __syncthreads();
    mlp_layer<NTE, 192, 256, 4, 4, true,  0, 4>(bufA, bufB, bufP, Wu1, bu1); __syncthreads();
    mlp_layer<NTE, 256, 256, 4, 4, true,  0, 4>(bufB, bufA, bufP, Wu2, bu2); __syncthreads();
    mlp_layer<NTE, 256, 128, 2, 4, false, 0, 4>(bufA, bufB, bufP, Wu3, bu3); __syncthreads();
    if (t < NTE * 4) {
        int e = t >> 2, f4 = (t & 3) * 4;
        int node = base + e;
        float4 v = make_float4(0.f, 0.f, 0.f, 0.f);
        if (node < n_agents) v = *(const float4*)(actions + (size_t)node * 16 + f4);
        *(float4*)(bufA + e * STRIDE + f4) = v;
    }
    __syncthreads();
    mlp_layer<NTE, 16,  128, 2, 4, true, 128, 1>(bufA, bufB, bufP, Wact, bact); __syncthreads();
    mlp_layer<NTE, 256, 256, 4, 4, true, 0,   4>(bufB, bufA, bufP, Wh1, bh1); __syncthreads();
    mlp_layer<NTE, 256, 256, 4, 4, true, 0,   4>(bufA, bufB, bufP, Wh2, bh2); __syncthreads();
    {
        int wv = t >> 6, lane = t & 63;
        int node = base + wv;
        float4 z = *(const float4*)(bufB + wv * STRIDE + lane * 4);
        float4 qw = *(const float4*)(Wq + lane * 4);
        float p = z.x * qw.x + z.y * qw.y + z.z * qw.z + z.w * qw.w;
#pragma unroll
        for (int off = 32; off >= 1; off >>= 1) p += __shfl_down(p, off, 64);
        if (lane == 0 && node < n_agents) out[node] = p + bq[0];
    }
}

extern "C" void kernel_launch(void* const* d_in, const int* in_sizes, int n_in,
                              void* d_out, int out_size, void* d_ws, size_t ws_size,
                              hipStream_t stream) {
    const float* x        = (const float*)d_in[0];
    const float* actions  = (const float*)d_in[1];
    const int*   senders  = (const int*)d_in[2];
    const int*   receivers= (const int*)d_in[3];
    const float* Wm1 = (const float*)d_in[5],  *bm1 = (const float*)d_in[6];
    const float* Wm2 = (const float*)d_in[7],  *bm2 = (const float*)d_in[8];
    const float* Wm3 = (const float*)d_in[9],  *bm3 = (const float*)d_in[10];
    const float* Wa1 = (const float*)d_in[11], *ba1 = (const float*)d_in[12];
    const float* Wa2 = (const float*)d_in[13], *ba2 = (const float*)d_in[14];
    const float* Wa3 = (const float*)d_in[15], *ba3 = (const float*)d_in[16];
    const float* Wu1 = (const float*)d_in[17], *bu1 = (const float*)d_in[18];
    const float* Wu2 = (const float*)d_in[19], *bu2 = (const float*)d_in[20];
    const float* Wu3 = (const float*)d_in[21], *bu3 = (const float*)d_in[22];
    const float* Wact= (const float*)d_in[23], *bact= (const float*)d_in[24];
    const float* Wh1 = (const float*)d_in[25], *bh1 = (const float*)d_in[26];
    const float* Wh2 = (const float*)d_in[27], *bh2 = (const float*)d_in[28];
    const float* Wq  = (const float*)d_in[29], *bq  = (const float*)d_in[30];

    const int E = in_sizes[2];
    const int n_agents = out_size;

    // ws layout: [0,4) counter | [1024, +512K) aggr | [525312, +512K) packed W
    //            | [1049600, ...) edges
    char* ws = (char*)d_ws;
    int*   counter = (int*)ws;
    float* aggr    = (float*)(ws + 1024);
    const size_t packOff = 1024 + (size_t)n_agents * 128 * sizeof(float); // 525312
    uint*  pack    = (uint*)(ws + packOff);
    const size_t edgeOff = packOff + 524288;
    int2*  edges   = (int2*)(ws + edgeOff);
    int cap = (int)((ws_size > edgeOff) ? (ws_size - edgeOff) / sizeof(int2) : 0);
    if (cap > E) cap = E;

    hipMemsetAsync(ws, 0, packOff, stream);   // counter + aggr

    pack_weights<<<64, 256, 0, stream>>>(Wm1, Wm2, Wm3, pack);

    int fblocks = (E + FILT_CHUNK - 1) / FILT_CHUNK;
    filter_edges<<<fblocks, 256, 0, stream>>>(senders, receivers, E, n_agents,
                                              cap, counter, edges);

    edge_mlp<<<512, 256, 0, stream>>>(x, edges, counter, cap, aggr, pack,
                                      bm1, bm2, bm3);

    node_update<<<(n_agents + NTE - 1) / NTE, 256, 0, stream>>>(
        x, actions, aggr, n_agents,
        Wa1, ba1, Wa2, ba2, Wa3, ba3,
        Wu1, bu1, Wu2, bu2, Wu3, bu3,
        Wact, bact, Wh1, bh1, Wh2, bh2, Wq, bq,
        (float*)d_out);
}